// Round 1
// baseline (1378.593 us; speedup 1.0000x reference)
//
#include <hip/hip_runtime.h>
#include <cstdint>
#include <cstddef>

typedef float  f32x4  __attribute__((ext_vector_type(4)));
typedef __bf16 bf16x8 __attribute__((ext_vector_type(8)));
typedef unsigned short u16x8 __attribute__((ext_vector_type(8)));
typedef unsigned short u16x4 __attribute__((ext_vector_type(4)));
typedef unsigned short u16x2 __attribute__((ext_vector_type(2)));

#define DEV static __device__ __forceinline__

DEV unsigned short f2bfu(float f) { __bf16 b = (__bf16)f; return __builtin_bit_cast(unsigned short, b); }
DEV float bfu2f(unsigned short u) { return (float)__builtin_bit_cast(__bf16, u); }
DEV bf16x8 ldb8(const unsigned short* p) { return __builtin_bit_cast(bf16x8, *(const u16x8*)p); }

DEV f32x4 mfma16(bf16x8 a, bf16x8 b, f32x4 c) {
  return __builtin_amdgcn_mfma_f32_16x16x32_bf16(a, b, c, 0, 0, 0);
}

// ---------------------------------------------------------------------------
// Generic GEMM: C[M,N] = A[M,K](bf16) @ B[N,K](f32, transposed weight)^T
// 128x128 tile, BK=32, 4 waves, each wave 64x64 (4x4 frags of 16x16x32 MFMA).
// EPI: 0 = store bf16 (ldc)
//      1 = store bf16 transposed V layout: vt[(b*2048+n)*2048 + s], m=b*2048+s
//      2 = store f32 = aux_f32[m*ldc+n] + acc   (o-proj residual)
//      3 = gate: read a=aux_bf16[m*ldc+n]; store bf16 silu(a)*acc
//      4 = f32 accumulate: C[m*ldc+n] += acc    (final FFN residual add)
// ---------------------------------------------------------------------------
template<int EPI>
__global__ __launch_bounds__(256) void gemm_bt(
    const unsigned short* __restrict__ A, const float* __restrict__ B,
    void* __restrict__ Cv, const void* __restrict__ aux,
    int M, int N, int K, int ldc)
{
  __shared__ __align__(16) unsigned short As[128 * 40];
  __shared__ __align__(16) unsigned short Bs[128 * 40];
  const int tid  = threadIdx.x;
  const int lane = tid & 63;
  const int w    = tid >> 6;
  const int wr   = w >> 1, wc = w & 1;
  const int l15  = lane & 15, lg = lane >> 4;
  const int m0 = blockIdx.x * 128, n0 = blockIdx.y * 128;

  f32x4 zero = {0.f, 0.f, 0.f, 0.f};
  f32x4 acc[4][4];
#pragma unroll
  for (int i = 0; i < 4; i++)
#pragma unroll
    for (int j = 0; j < 4; j++) acc[i][j] = zero;

  for (int k0 = 0; k0 < K; k0 += 32) {
    // stage A tile (bf16 source): 128 rows x 32 cols
#pragma unroll
    for (int p = 0; p < 2; ++p) {
      int idx = p * 256 + tid;
      int row = idx >> 2, colg = idx & 3;
      u16x8 av = *(const u16x8*)(A + (size_t)(m0 + row) * K + k0 + colg * 8);
      *(u16x8*)(As + row * 40 + colg * 8) = av;
    }
    // stage B tile (f32 source, convert to bf16): 128 rows x 32 cols
#pragma unroll
    for (int p = 0; p < 4; ++p) {
      int idx = p * 256 + tid;
      int row = idx >> 3, colg = idx & 7;
      int gn = n0 + row; if (gn >= N) gn = N - 1;
      f32x4 bv = *(const f32x4*)(B + (size_t)gn * K + k0 + colg * 4);
      u16x4 bb = { f2bfu(bv.x), f2bfu(bv.y), f2bfu(bv.z), f2bfu(bv.w) };
      *(u16x4*)(Bs + row * 40 + colg * 4) = bb;
    }
    __syncthreads();
    bf16x8 af[4], bfr[4];
#pragma unroll
    for (int mi = 0; mi < 4; mi++)
      af[mi] = ldb8(As + (wr * 64 + mi * 16 + l15) * 40 + lg * 8);
#pragma unroll
    for (int ni = 0; ni < 4; ni++)
      bfr[ni] = ldb8(Bs + (wc * 64 + ni * 16 + l15) * 40 + lg * 8);
#pragma unroll
    for (int mi = 0; mi < 4; mi++)
#pragma unroll
      for (int ni = 0; ni < 4; ni++)
        acc[mi][ni] = mfma16(af[mi], bfr[ni], acc[mi][ni]);
    __syncthreads();
  }

  // epilogue: C/D layout col = lane&15, row = (lane>>4)*4 + r
#pragma unroll
  for (int mi = 0; mi < 4; mi++) {
#pragma unroll
    for (int ni = 0; ni < 4; ni++) {
#pragma unroll
      for (int r = 0; r < 4; r++) {
        int row = m0 + wr * 64 + mi * 16 + lg * 4 + r;
        int col = n0 + wc * 64 + ni * 16 + l15;
        if (col >= N) continue;
        float v = acc[mi][ni][r];
        if constexpr (EPI == 0) {
          ((unsigned short*)Cv)[(size_t)row * ldc + col] = f2bfu(v);
        } else if constexpr (EPI == 1) {
          int bb_ = row >> 11, ss = row & 2047;
          ((unsigned short*)Cv)[((size_t)(bb_ * 2048 + col)) * 2048 + ss] = f2bfu(v);
        } else if constexpr (EPI == 2) {
          const float* xx = (const float*)aux;
          ((float*)Cv)[(size_t)row * ldc + col] = xx[(size_t)row * ldc + col] + v;
        } else if constexpr (EPI == 3) {
          const unsigned short* a1 = (const unsigned short*)aux;
          float a = bfu2f(a1[(size_t)row * ldc + col]);
          float sg = a / (1.0f + expf(-a));
          ((unsigned short*)Cv)[(size_t)row * ldc + col] = f2bfu(sg * v);
        } else if constexpr (EPI == 4) {
          float* C = (float*)Cv;
          size_t ix = (size_t)row * ldc + col;
          C[ix] = C[ix] + v;
        }
      }
    }
  }
}

// ---------------------------------------------------------------------------
// RMSNorm: one block (256 thr) per row of 2048 f32 -> bf16 out
// ---------------------------------------------------------------------------
__global__ __launch_bounds__(256) void rmsnorm_k(
    const float* __restrict__ x, const float* __restrict__ g,
    unsigned short* __restrict__ out)
{
  int row = blockIdx.x, t = threadIdx.x;
  const float* xr = x + (size_t)row * 2048;
  f32x4 v0 = ((const f32x4*)xr)[t];
  f32x4 v1 = ((const f32x4*)xr)[t + 256];
  float ss = v0.x*v0.x + v0.y*v0.y + v0.z*v0.z + v0.w*v0.w
           + v1.x*v1.x + v1.y*v1.y + v1.z*v1.z + v1.w*v1.w;
  __shared__ float red[256];
  red[t] = ss; __syncthreads();
  for (int sh = 128; sh > 0; sh >>= 1) {
    if (t < sh) red[t] += red[t + sh];
    __syncthreads();
  }
  float rinv = rsqrtf(red[0] * (1.0f / 2048.0f) + 1e-5f);
  f32x4 g0 = ((const f32x4*)g)[t];
  f32x4 g1 = ((const f32x4*)g)[t + 256];
  u16x4 o0 = { f2bfu(v0.x*rinv*g0.x), f2bfu(v0.y*rinv*g0.y),
               f2bfu(v0.z*rinv*g0.z), f2bfu(v0.w*rinv*g0.w) };
  u16x4 o1 = { f2bfu(v1.x*rinv*g1.x), f2bfu(v1.y*rinv*g1.y),
               f2bfu(v1.z*rinv*g1.z), f2bfu(v1.w*rinv*g1.w) };
  *(u16x4*)(out + (size_t)row * 2048 + t * 4) = o0;
  *(u16x4*)(out + (size_t)row * 2048 + 1024 + t * 4) = o1;
}

// ---------------------------------------------------------------------------
// RoPE table: cos/sin for (s, p) s<2048, p<64.  ang = s * theta^(-p/64)
// ---------------------------------------------------------------------------
__global__ __launch_bounds__(256) void rope_tab(float* __restrict__ cosT,
                                                float* __restrict__ sinT)
{
  int idx = blockIdx.x * 256 + threadIdx.x;   // < 131072
  int s = idx >> 6, p = idx & 63;
  float ang = (float)s * powf(10000.0f, -(float)p / 64.0f);
  cosT[idx] = cosf(ang);
  sinT[idx] = sinf(ang);
}

// ---------------------------------------------------------------------------
// RoPE apply in-place on (4096 rows x 2048 cols) bf16, head dim 128
// ---------------------------------------------------------------------------
__global__ __launch_bounds__(256) void rope_apply(
    unsigned short* __restrict__ t, const float* __restrict__ cosT,
    const float* __restrict__ sinT)
{
  int idx = blockIdx.x * 256 + threadIdx.x;   // < 4096*1024 pairs
  int row = idx >> 10, pp = idx & 1023;
  int s = row & 2047;
  int p = pp & 63;
  float c  = cosT[s * 64 + p];
  float sn = sinT[s * 64 + p];
  unsigned short* ptr = t + (size_t)row * 2048 + pp * 2;
  u16x2 eo = *(u16x2*)ptr;
  float e = bfu2f(eo.x), o = bfu2f(eo.y);
  u16x2 res = { f2bfu(e * c - o * sn), f2bfu(e * sn + o * c) };
  *(u16x2*)ptr = res;
}

// ---------------------------------------------------------------------------
// Flash attention, causal. 1 wave per block, 16 q-rows per block.
// q,k: (B*S, 2048) bf16 row-major (head-major cols). vt: (B*2048, 2048) bf16,
// vt[(b*2048 + h*128 + d)*2048 + s].  o: like q.
// ---------------------------------------------------------------------------
__global__ __launch_bounds__(64) void attn_fwd(
    const unsigned short* __restrict__ q, const unsigned short* __restrict__ k,
    const unsigned short* __restrict__ vt, unsigned short* __restrict__ o)
{
  const int S = 2048, Dm = 2048, DK = 128;
  const int lane = threadIdx.x;
  const int qt = blockIdx.x, hh = blockIdx.y, b = blockIdx.z;
  const int r0 = qt * 16;
  const int l15 = lane & 15, lg = lane >> 4;
  const float SCALE = 0.08838834764831845f;  // 1/sqrt(128)

  __shared__ __align__(16) unsigned short P_lds[16 * 40];

  bf16x8 qf[4];
  size_t qbase = ((size_t)(b * S + r0 + l15)) * Dm + hh * DK + lg * 8;
#pragma unroll
  for (int kk = 0; kk < 4; kk++) qf[kk] = ldb8(q + qbase + kk * 32);

  f32x4 zero = {0.f, 0.f, 0.f, 0.f};
  f32x4 accO[8];
#pragma unroll
  for (int dt = 0; dt < 8; dt++) accO[dt] = zero;
  float mrow[4] = {-1e30f, -1e30f, -1e30f, -1e30f};
  float lrow[4] = {0.f, 0.f, 0.f, 0.f};

  int nkv = (r0 + 15) / 32 + 1;
  for (int j = 0; j < nkv; ++j) {
    int kv0 = j * 32;
    f32x4 s0 = zero, s1 = zero;
    size_t kbase = ((size_t)(b * S + kv0 + l15)) * Dm + hh * DK + lg * 8;
#pragma unroll
    for (int kk = 0; kk < 4; kk++) {
      bf16x8 k0f = ldb8(k + kbase + kk * 32);
      bf16x8 k1f = ldb8(k + kbase + (size_t)16 * Dm + kk * 32);
      s0 = mfma16(qf[kk], k0f, s0);
      s1 = mfma16(qf[kk], k1f, s1);
    }
    float alpha[4], p0[4], p1[4];
#pragma unroll
    for (int r = 0; r < 4; r++) {
      int qr = r0 + lg * 4 + r;
      int c0 = kv0 + l15;
      float a0  = (c0      <= qr) ? s0[r] * SCALE : -1e30f;
      float a1v = (c0 + 16 <= qr) ? s1[r] * SCALE : -1e30f;
      float mx = fmaxf(a0, a1v);
#pragma unroll
      for (int off = 1; off < 16; off <<= 1) mx = fmaxf(mx, __shfl_xor(mx, off));
      float mnew = fmaxf(mrow[r], mx);
      alpha[r] = expf(mrow[r] - mnew);
      p0[r] = expf(a0 - mnew);
      p1[r] = expf(a1v - mnew);
      float ps = p0[r] + p1[r];
#pragma unroll
      for (int off = 1; off < 16; off <<= 1) ps += __shfl_xor(ps, off);
      lrow[r] = lrow[r] * alpha[r] + ps;
      mrow[r] = mnew;
    }
#pragma unroll
    for (int dt = 0; dt < 8; dt++) {
      f32x4 t = accO[dt];
      t[0] *= alpha[0]; t[1] *= alpha[1]; t[2] *= alpha[2]; t[3] *= alpha[3];
      accO[dt] = t;
    }
    __syncthreads();
#pragma unroll
    for (int r = 0; r < 4; r++) {
      int prow = lg * 4 + r;
      P_lds[prow * 40 + l15]      = f2bfu(p0[r]);
      P_lds[prow * 40 + 16 + l15] = f2bfu(p1[r]);
    }
    __syncthreads();
    bf16x8 pa = ldb8(P_lds + l15 * 40 + lg * 8);
    size_t vtb = ((size_t)((b * 16 + hh) * 128 + l15)) * S + kv0 + lg * 8;
#pragma unroll
    for (int dt = 0; dt < 8; dt++) {
      bf16x8 vb = ldb8(vt + vtb + (size_t)dt * 16 * S);
      accO[dt] = mfma16(pa, vb, accO[dt]);
    }
  }
#pragma unroll
  for (int dt = 0; dt < 8; dt++) {
#pragma unroll
    for (int r = 0; r < 4; r++) {
      int qr = r0 + lg * 4 + r;
      o[((size_t)(b * S + qr)) * Dm + hh * DK + dt * 16 + l15] =
          f2bfu(accO[dt][r] / lrow[r]);
    }
  }
}

// ---------------------------------------------------------------------------
extern "C" void kernel_launch(void* const* d_in, const int* in_sizes, int n_in,
                              void* d_out, int out_size, void* d_ws, size_t ws_size,
                              hipStream_t stream)
{
  const float* x      = (const float*)d_in[0];
  const float* wq     = (const float*)d_in[1];
  const float* wk     = (const float*)d_in[2];
  const float* wv     = (const float*)d_in[3];
  const float* wo     = (const float*)d_in[4];
  const float* w1     = (const float*)d_in[5];
  const float* w2     = (const float*)d_in[6];
  const float* w3     = (const float*)d_in[7];
  const float* g_attn = (const float*)d_in[8];
  const float* g_ffn  = (const float*)d_in[9];
  float* out = (float*)d_out;

  char* ws = (char*)d_ws;
  unsigned short* h_bf  = (unsigned short*)ws;
  unsigned short* q_bf  = h_bf  + 8388608;
  unsigned short* k_bf  = q_bf  + 8388608;
  unsigned short* vt_bf = k_bf  + 8388608;
  unsigned short* o_bf  = vt_bf + 8388608;
  unsigned short* a1_bf = o_bf  + 8388608;   // 4096*5440
  float* cosT = (float*)(ws + (size_t)(8388608ull * 5 + 22282240ull) * 2);
  float* sinT = cosT + 131072;

  dim3 blk(256);
  rope_tab<<<512, blk, 0, stream>>>(cosT, sinT);
  rmsnorm_k<<<4096, blk, 0, stream>>>(x, g_attn, h_bf);

  dim3 g16(32, 16);
  gemm_bt<0><<<g16, blk, 0, stream>>>(h_bf, wq, q_bf, nullptr, 4096, 2048, 2048, 2048);
  gemm_bt<0><<<g16, blk, 0, stream>>>(h_bf, wk, k_bf, nullptr, 4096, 2048, 2048, 2048);
  gemm_bt<1><<<g16, blk, 0, stream>>>(h_bf, wv, vt_bf, nullptr, 4096, 2048, 2048, 2048);

  rope_apply<<<16384, blk, 0, stream>>>(q_bf, cosT, sinT);
  rope_apply<<<16384, blk, 0, stream>>>(k_bf, cosT, sinT);

  dim3 ga(128, 16, 2);
  attn_fwd<<<ga, dim3(64), 0, stream>>>(q_bf, k_bf, vt_bf, o_bf);

  gemm_bt<2><<<g16, blk, 0, stream>>>(o_bf, wo, out, x, 4096, 2048, 2048, 2048);
  rmsnorm_k<<<4096, blk, 0, stream>>>(out, g_ffn, h_bf);

  dim3 gf(32, 43);
  gemm_bt<0><<<gf, blk, 0, stream>>>(h_bf, w1, a1_bf, nullptr, 4096, 5440, 2048, 5440);
  gemm_bt<3><<<gf, blk, 0, stream>>>(h_bf, w3, a1_bf, a1_bf, 4096, 5440, 2048, 5440);
  gemm_bt<4><<<g16, blk, 0, stream>>>(a1_bf, w2, out, nullptr, 4096, 2048, 5440, 2048);
}

// Round 2
// 1160.134 us; speedup vs baseline: 1.1883x; 1.1883x over previous
//
#include <hip/hip_runtime.h>
#include <cstdint>
#include <cstddef>

typedef float  f32x4  __attribute__((ext_vector_type(4)));
typedef __bf16 bf16x8 __attribute__((ext_vector_type(8)));
typedef unsigned short u16x8 __attribute__((ext_vector_type(8)));
typedef unsigned short u16x4 __attribute__((ext_vector_type(4)));
typedef unsigned short u16x2 __attribute__((ext_vector_type(2)));

#define DEV static __device__ __forceinline__

DEV unsigned short f2bfu(float f) { __bf16 b = (__bf16)f; return __builtin_bit_cast(unsigned short, b); }
DEV float bfu2f(unsigned short u) { return (float)__builtin_bit_cast(__bf16, u); }
DEV bf16x8 ldb8(const unsigned short* p) { return __builtin_bit_cast(bf16x8, *(const u16x8*)p); }

DEV f32x4 mfma16(bf16x8 a, bf16x8 b, f32x4 c) {
  return __builtin_amdgcn_mfma_f32_16x16x32_bf16(a, b, c, 0, 0, 0);
}

// ---------------------------------------------------------------------------
// Generic GEMM: C[M,N] = A[M,K](bf16) @ B[N,K](f32, transposed weight)^T
// 128x128 tile, BK=32, 4 waves, each wave 64x64 (4x4 frags of 16x16x32 MFMA).
// EPI: 0 = store bf16 (ldc)
//      1 = store bf16 transposed V layout: vt[(b*2048+n)*2048 + s], m=b*2048+s
//      2 = store f32 = aux_f32[m*ldc+n] + acc   (o-proj residual)
//      3 = gate: read a=aux_bf16[m*ldc+n]; store bf16 silu(a)*acc
//      4 = f32 accumulate: C[m*ldc+n] += acc    (final FFN residual add)
// ---------------------------------------------------------------------------
template<int EPI>
__global__ __launch_bounds__(256) void gemm_bt(
    const unsigned short* __restrict__ A, const float* __restrict__ B,
    void* __restrict__ Cv, const void* __restrict__ aux,
    int M, int N, int K, int ldc)
{
  __shared__ __align__(16) unsigned short As[128 * 40];
  __shared__ __align__(16) unsigned short Bs[128 * 40];
  const int tid  = threadIdx.x;
  const int lane = tid & 63;
  const int w    = tid >> 6;
  const int wr   = w >> 1, wc = w & 1;
  const int l15  = lane & 15, lg = lane >> 4;
  const int m0 = blockIdx.x * 128, n0 = blockIdx.y * 128;

  f32x4 zero = {0.f, 0.f, 0.f, 0.f};
  f32x4 acc[4][4];
#pragma unroll
  for (int i = 0; i < 4; i++)
#pragma unroll
    for (int j = 0; j < 4; j++) acc[i][j] = zero;

  for (int k0 = 0; k0 < K; k0 += 32) {
#pragma unroll
    for (int p = 0; p < 2; ++p) {
      int idx = p * 256 + tid;
      int row = idx >> 2, colg = idx & 3;
      u16x8 av = *(const u16x8*)(A + (size_t)(m0 + row) * K + k0 + colg * 8);
      *(u16x8*)(As + row * 40 + colg * 8) = av;
    }
#pragma unroll
    for (int p = 0; p < 4; ++p) {
      int idx = p * 256 + tid;
      int row = idx >> 3, colg = idx & 7;
      int gn = n0 + row; if (gn >= N) gn = N - 1;
      f32x4 bv = *(const f32x4*)(B + (size_t)gn * K + k0 + colg * 4);
      u16x4 bb = { f2bfu(bv.x), f2bfu(bv.y), f2bfu(bv.z), f2bfu(bv.w) };
      *(u16x4*)(Bs + row * 40 + colg * 4) = bb;
    }
    __syncthreads();
    bf16x8 af[4], bfr[4];
#pragma unroll
    for (int mi = 0; mi < 4; mi++)
      af[mi] = ldb8(As + (wr * 64 + mi * 16 + l15) * 40 + lg * 8);
#pragma unroll
    for (int ni = 0; ni < 4; ni++)
      bfr[ni] = ldb8(Bs + (wc * 64 + ni * 16 + l15) * 40 + lg * 8);
#pragma unroll
    for (int mi = 0; mi < 4; mi++)
#pragma unroll
      for (int ni = 0; ni < 4; ni++)
        acc[mi][ni] = mfma16(af[mi], bfr[ni], acc[mi][ni]);
    __syncthreads();
  }

#pragma unroll
  for (int mi = 0; mi < 4; mi++) {
#pragma unroll
    for (int ni = 0; ni < 4; ni++) {
#pragma unroll
      for (int r = 0; r < 4; r++) {
        int row = m0 + wr * 64 + mi * 16 + lg * 4 + r;
        int col = n0 + wc * 64 + ni * 16 + l15;
        if (col >= N) continue;
        float v = acc[mi][ni][r];
        if constexpr (EPI == 0) {
          ((unsigned short*)Cv)[(size_t)row * ldc + col] = f2bfu(v);
        } else if constexpr (EPI == 1) {
          int bb_ = row >> 11, ss = row & 2047;
          ((unsigned short*)Cv)[((size_t)(bb_ * 2048 + col)) * 2048 + ss] = f2bfu(v);
        } else if constexpr (EPI == 2) {
          const float* xx = (const float*)aux;
          ((float*)Cv)[(size_t)row * ldc + col] = xx[(size_t)row * ldc + col] + v;
        } else if constexpr (EPI == 3) {
          const unsigned short* a1 = (const unsigned short*)aux;
          float a = bfu2f(a1[(size_t)row * ldc + col]);
          float sg = a / (1.0f + expf(-a));
          ((unsigned short*)Cv)[(size_t)row * ldc + col] = f2bfu(sg * v);
        } else if constexpr (EPI == 4) {
          float* C = (float*)Cv;
          size_t ix = (size_t)row * ldc + col;
          C[ix] = C[ix] + v;
        }
      }
    }
  }
}

// ---------------------------------------------------------------------------
// RMSNorm: one block (256 thr) per row of 2048 f32 -> bf16 out
// ---------------------------------------------------------------------------
__global__ __launch_bounds__(256) void rmsnorm_k(
    const float* __restrict__ x, const float* __restrict__ g,
    unsigned short* __restrict__ out)
{
  int row = blockIdx.x, t = threadIdx.x;
  const float* xr = x + (size_t)row * 2048;
  f32x4 v0 = ((const f32x4*)xr)[t];
  f32x4 v1 = ((const f32x4*)xr)[t + 256];
  float ss = v0.x*v0.x + v0.y*v0.y + v0.z*v0.z + v0.w*v0.w
           + v1.x*v1.x + v1.y*v1.y + v1.z*v1.z + v1.w*v1.w;
  __shared__ float red[256];
  red[t] = ss; __syncthreads();
  for (int sh = 128; sh > 0; sh >>= 1) {
    if (t < sh) red[t] += red[t + sh];
    __syncthreads();
  }
  float rinv = rsqrtf(red[0] * (1.0f / 2048.0f) + 1e-5f);
  f32x4 g0 = ((const f32x4*)g)[t];
  f32x4 g1 = ((const f32x4*)g)[t + 256];
  u16x4 o0 = { f2bfu(v0.x*rinv*g0.x), f2bfu(v0.y*rinv*g0.y),
               f2bfu(v0.z*rinv*g0.z), f2bfu(v0.w*rinv*g0.w) };
  u16x4 o1 = { f2bfu(v1.x*rinv*g1.x), f2bfu(v1.y*rinv*g1.y),
               f2bfu(v1.z*rinv*g1.z), f2bfu(v1.w*rinv*g1.w) };
  *(u16x4*)(out + (size_t)row * 2048 + t * 4) = o0;
  *(u16x4*)(out + (size_t)row * 2048 + 1024 + t * 4) = o1;
}

// ---------------------------------------------------------------------------
// RoPE table + apply (unchanged)
// ---------------------------------------------------------------------------
__global__ __launch_bounds__(256) void rope_tab(float* __restrict__ cosT,
                                                float* __restrict__ sinT)
{
  int idx = blockIdx.x * 256 + threadIdx.x;
  int s = idx >> 6, p = idx & 63;
  float ang = (float)s * powf(10000.0f, -(float)p / 64.0f);
  cosT[idx] = cosf(ang);
  sinT[idx] = sinf(ang);
}

__global__ __launch_bounds__(256) void rope_apply(
    unsigned short* __restrict__ t, const float* __restrict__ cosT,
    const float* __restrict__ sinT)
{
  int idx = blockIdx.x * 256 + threadIdx.x;
  int row = idx >> 10, pp = idx & 1023;
  int s = row & 2047;
  int p = pp & 63;
  float c  = cosT[s * 64 + p];
  float sn = sinT[s * 64 + p];
  unsigned short* ptr = t + (size_t)row * 2048 + pp * 2;
  u16x2 eo = *(u16x2*)ptr;
  float e = bfu2f(eo.x), o = bfu2f(eo.y);
  u16x2 res = { f2bfu(e * c - o * sn), f2bfu(e * sn + o * c) };
  *(u16x2*)ptr = res;
}

// ---------------------------------------------------------------------------
// Flash attention, causal. 4 waves/block, 64 q-rows/block (16 per wave).
// KVBLK=64. K-tile (64x128) and V^T-tile (128x64) staged in LDS, XOR-swizzled
// (byte ^= (row&7)<<4) to kill the row-major D=128 bank conflict.
// q,k: (B*S, 2048) bf16. vt: (B*2048, 2048) bf16, vt[(b*2048+h*128+d)*2048+s].
// ---------------------------------------------------------------------------
__global__ __launch_bounds__(256) void attn_fwd(
    const unsigned short* __restrict__ q, const unsigned short* __restrict__ k,
    const unsigned short* __restrict__ vt, unsigned short* __restrict__ o)
{
  const int S = 2048, Dm = 2048;
  const int tid  = threadIdx.x;
  const int lane = tid & 63;
  const int w    = tid >> 6;
  const int qt   = gridDim.x - 1 - blockIdx.x;   // big blocks first
  const int hh   = blockIdx.y, b = blockIdx.z;
  const int r0   = qt * 64;
  const int l15  = lane & 15, lg = lane >> 4;
  const float SCALE = 0.08838834764831845f;  // 1/sqrt(128)

  __shared__ __align__(16) unsigned short Ks[64 * 128];   // 16 KB, swizzled
  __shared__ __align__(16) unsigned short Vs[128 * 64];   // 16 KB, swizzled
  __shared__ __align__(16) unsigned short Ps[4][16 * 76]; // wave-private P

  // Q fragments: wave w owns q rows r0 + w*16 .. +15
  bf16x8 qf[4];
  size_t qbase = ((size_t)(b * S + r0 + w * 16 + l15)) * Dm + hh * 128 + lg * 8;
#pragma unroll
  for (int kk = 0; kk < 4; kk++) qf[kk] = ldb8(q + qbase + kk * 32);

  f32x4 zero = {0.f, 0.f, 0.f, 0.f};
  f32x4 accO[8];
#pragma unroll
  for (int dt = 0; dt < 8; dt++) accO[dt] = zero;
  float mrow[4] = {-1e30f, -1e30f, -1e30f, -1e30f};
  float lrow[4] = {0.f, 0.f, 0.f, 0.f};

  const unsigned short* kg = k  + ((size_t)(b * S)) * Dm + hh * 128;
  const unsigned short* vg = vt + ((size_t)((b * 16 + hh) * 128)) * S;

  int ntile = qt + 1;
  for (int j = 0; j < ntile; ++j) {
    int kv0 = j * 64;
    // --- stage K tile: 64 rows x 128 cols bf16, swizzled
#pragma unroll
    for (int i = 0; i < 4; i++) {
      int idx = i * 256 + tid;
      int row = idx >> 4, slot = idx & 15;
      u16x8 vv = *(const u16x8*)(kg + (size_t)(kv0 + row) * Dm + slot * 8);
      int boff = (row * 256 + slot * 16) ^ ((row & 7) << 4);
      *(u16x8*)((char*)Ks + boff) = vv;
    }
    // --- stage V^T tile: 128 rows(d) x 64 cols(kv), swizzled
#pragma unroll
    for (int i = 0; i < 4; i++) {
      int idx = i * 256 + tid;
      int row = idx >> 3, slot = idx & 7;
      u16x8 vv = *(const u16x8*)(vg + (size_t)row * S + kv0 + slot * 8);
      int boff = (row * 128 + slot * 16) ^ ((row & 7) << 4);
      *(u16x8*)((char*)Vs + boff) = vv;
    }
    __syncthreads();

    // --- QK^T: 4 kv quadrants of 16
    f32x4 sfr[4];
#pragma unroll
    for (int sv = 0; sv < 4; sv++) sfr[sv] = zero;
#pragma unroll
    for (int kk = 0; kk < 4; kk++) {
#pragma unroll
      for (int sv = 0; sv < 4; sv++) {
        int row = sv * 16 + l15;
        int boff = (row * 256 + kk * 64 + lg * 16) ^ ((row & 7) << 4);
        bf16x8 kf = ldb8((const unsigned short*)((const char*)Ks + boff));
        sfr[sv] = mfma16(qf[kk], kf, sfr[sv]);
      }
    }

    // --- online softmax over 64 columns
    float alpha[4];
    float pv[4][4];
#pragma unroll
    for (int r = 0; r < 4; r++) {
      int qr = r0 + w * 16 + lg * 4 + r;
      float a[4];
#pragma unroll
      for (int sv = 0; sv < 4; sv++)
        a[sv] = (kv0 + sv * 16 + l15 <= qr) ? sfr[sv][r] * SCALE : -1e30f;
      float mx = fmaxf(fmaxf(a[0], a[1]), fmaxf(a[2], a[3]));
#pragma unroll
      for (int off = 1; off < 16; off <<= 1) mx = fmaxf(mx, __shfl_xor(mx, off));
      float mnew = fmaxf(mrow[r], mx);
      alpha[r] = expf(mrow[r] - mnew);
      float ps = 0.f;
#pragma unroll
      for (int sv = 0; sv < 4; sv++) { pv[r][sv] = expf(a[sv] - mnew); ps += pv[r][sv]; }
#pragma unroll
      for (int off = 1; off < 16; off <<= 1) ps += __shfl_xor(ps, off);
      lrow[r] = lrow[r] * alpha[r] + ps;
      mrow[r] = mnew;
    }
#pragma unroll
    for (int dt = 0; dt < 8; dt++) {
      f32x4 t = accO[dt];
      t[0] *= alpha[0]; t[1] *= alpha[1]; t[2] *= alpha[2]; t[3] *= alpha[3];
      accO[dt] = t;
    }

    // --- P to LDS (wave-private), then PV
#pragma unroll
    for (int r = 0; r < 4; r++)
#pragma unroll
      for (int sv = 0; sv < 4; sv++)
        Ps[w][(lg * 4 + r) * 76 + sv * 16 + l15] = f2bfu(pv[r][sv]);
    __syncthreads();

    bf16x8 pa[2];
    pa[0] = ldb8(&Ps[w][l15 * 76 + lg * 8]);
    pa[1] = ldb8(&Ps[w][l15 * 76 + 32 + lg * 8]);
#pragma unroll
    for (int dt = 0; dt < 8; dt++) {
#pragma unroll
      for (int kk = 0; kk < 2; kk++) {
        int row = dt * 16 + l15;
        int boff = (row * 128 + kk * 64 + lg * 16) ^ ((row & 7) << 4);
        bf16x8 vb = ldb8((const unsigned short*)((const char*)Vs + boff));
        accO[dt] = mfma16(pa[kk], vb, accO[dt]);
      }
    }
    __syncthreads();
  }

#pragma unroll
  for (int dt = 0; dt < 8; dt++) {
#pragma unroll
    for (int r = 0; r < 4; r++) {
      int qr = r0 + w * 16 + lg * 4 + r;
      o[((size_t)(b * S + qr)) * Dm + hh * 128 + dt * 16 + l15] =
          f2bfu(accO[dt][r] / lrow[r]);
    }
  }
}

// ---------------------------------------------------------------------------
extern "C" void kernel_launch(void* const* d_in, const int* in_sizes, int n_in,
                              void* d_out, int out_size, void* d_ws, size_t ws_size,
                              hipStream_t stream)
{
  const float* x      = (const float*)d_in[0];
  const float* wq     = (const float*)d_in[1];
  const float* wk     = (const float*)d_in[2];
  const float* wv     = (const float*)d_in[3];
  const float* wo     = (const float*)d_in[4];
  const float* w1     = (const float*)d_in[5];
  const float* w2     = (const float*)d_in[6];
  const float* w3     = (const float*)d_in[7];
  const float* g_attn = (const float*)d_in[8];
  const float* g_ffn  = (const float*)d_in[9];
  float* out = (float*)d_out;

  char* ws = (char*)d_ws;
  unsigned short* h_bf  = (unsigned short*)ws;
  unsigned short* q_bf  = h_bf  + 8388608;
  unsigned short* k_bf  = q_bf  + 8388608;
  unsigned short* vt_bf = k_bf  + 8388608;
  unsigned short* o_bf  = vt_bf + 8388608;
  unsigned short* a1_bf = o_bf  + 8388608;   // 4096*5440
  float* cosT = (float*)(ws + (size_t)(8388608ull * 5 + 22282240ull) * 2);
  float* sinT = cosT + 131072;

  dim3 blk(256);
  rope_tab<<<512, blk, 0, stream>>>(cosT, sinT);
  rmsnorm_k<<<4096, blk, 0, stream>>>(x, g_attn, h_bf);

  dim3 g16(32, 16);
  gemm_bt<0><<<g16, blk, 0, stream>>>(h_bf, wq, q_bf, nullptr, 4096, 2048, 2048, 2048);
  gemm_bt<0><<<g16, blk, 0, stream>>>(h_bf, wk, k_bf, nullptr, 4096, 2048, 2048, 2048);
  gemm_bt<1><<<g16, blk, 0, stream>>>(h_bf, wv, vt_bf, nullptr, 4096, 2048, 2048, 2048);

  rope_apply<<<16384, blk, 0, stream>>>(q_bf, cosT, sinT);
  rope_apply<<<16384, blk, 0, stream>>>(k_bf, cosT, sinT);

  dim3 ga(32, 16, 2);
  attn_fwd<<<ga, blk, 0, stream>>>(q_bf, k_bf, vt_bf, o_bf);

  gemm_bt<2><<<g16, blk, 0, stream>>>(o_bf, wo, out, x, 4096, 2048, 2048, 2048);
  rmsnorm_k<<<4096, blk, 0, stream>>>(out, g_ffn, h_bf);

  dim3 gf(32, 43);
  gemm_bt<0><<<gf, blk, 0, stream>>>(h_bf, w1, a1_bf, nullptr, 4096, 5440, 2048, 5440);
  gemm_bt<3><<<gf, blk, 0, stream>>>(h_bf, w3, a1_bf, a1_bf, 4096, 5440, 2048, 5440);
  gemm_bt<4><<<g16, blk, 0, stream>>>(a1_bf, w2, out, nullptr, 4096, 2048, 5440, 2048);
}

// Round 3
// 784.503 us; speedup vs baseline: 1.7573x; 1.4788x over previous
//
#include <hip/hip_runtime.h>
#include <cstdint>
#include <cstddef>

typedef float  f32x4  __attribute__((ext_vector_type(4)));
typedef __bf16 bf16x8 __attribute__((ext_vector_type(8)));
typedef unsigned short u16x8 __attribute__((ext_vector_type(8)));
typedef unsigned short u16x4 __attribute__((ext_vector_type(4)));

#define DEV static __device__ __forceinline__

DEV unsigned short f2bfu(float f) { __bf16 b = (__bf16)f; return __builtin_bit_cast(unsigned short, b); }
DEV float bfu2f(unsigned short u) { return (float)__builtin_bit_cast(__bf16, u); }
DEV bf16x8 ldb8(const unsigned short* p) { return __builtin_bit_cast(bf16x8, *(const u16x8*)p); }
DEV float fexp(float x) { return __builtin_amdgcn_exp2f(x * 1.44269504f); }

DEV f32x4 mfma16(bf16x8 a, bf16x8 b, f32x4 c) {
  return __builtin_amdgcn_mfma_f32_16x16x32_bf16(a, b, c, 0, 0, 0);
}

DEV void gload16(const void* g, void* l) {
  __builtin_amdgcn_global_load_lds((const unsigned int*)g, (unsigned int*)l, 16, 0, 0);
}

// ---------------------------------------------------------------------------
// Weight conversion kernels (f32 -> bf16), run once up-front.
// ---------------------------------------------------------------------------
__global__ __launch_bounds__(256) void conv_cat3(
    const float* __restrict__ s0, const float* __restrict__ s1,
    const float* __restrict__ s2, unsigned short* __restrict__ d)
{
  size_t i = (size_t)blockIdx.x * 256 + threadIdx.x;   // 3145728 groups of 4
  size_t e = i * 4;
  const float* s = e < 4194304 ? s0 : (e < 8388608 ? s1 : s2);
  f32x4 v = *(const f32x4*)(s + (e & 4194303));
  u16x4 o = { f2bfu(v.x), f2bfu(v.y), f2bfu(v.z), f2bfu(v.w) };
  *(u16x4*)(d + e) = o;
}

__global__ __launch_bounds__(256) void conv_plain(
    const float* __restrict__ s, unsigned short* __restrict__ d)
{
  size_t e = ((size_t)blockIdx.x * 256 + threadIdx.x) * 4;
  f32x4 v = *(const f32x4*)(s + e);
  u16x4 o = { f2bfu(v.x), f2bfu(v.y), f2bfu(v.z), f2bfu(v.w) };
  *(u16x4*)(d + e) = o;
}

// interleave w1/w3 rows in 16-row groups: logical row n -> grp=n>>4 even: w1,
// odd: w3, source row (grp>>1)*16 + (n&15)
__global__ __launch_bounds__(256) void conv_w13(
    const float* __restrict__ w1, const float* __restrict__ w3,
    unsigned short* __restrict__ d)
{
  size_t i = (size_t)blockIdx.x * 256 + threadIdx.x;   // 5570560 groups
  size_t e = i * 4;
  int n = (int)(e >> 11), kc = (int)(e & 2047);
  int grp = n >> 4;
  const float* s = (grp & 1) ? w3 : w1;
  size_t off = ((size_t)((grp >> 1) * 16 + (n & 15))) * 2048 + kc;
  f32x4 v = *(const f32x4*)(s + off);
  u16x4 o = { f2bfu(v.x), f2bfu(v.y), f2bfu(v.z), f2bfu(v.w) };
  *(u16x4*)(d + e) = o;
}

// ---------------------------------------------------------------------------
// GEMM core: C[M,N] = A[M,K](bf16) @ B[N,K](bf16)^T
// 128x128 tile, BK=64, 4 waves, global_load_lds(16B) staging with
// pre-swizzled global source; ds_read slot ^= (row&7) -> conflict-free.
// EPI 0: QKV fused + RoPE. D0=q, D1=k, D2=vt (transposed V). cols: [0,2048)q
//        [2048,4096)k [4096,6144)v.
// EPI 1: OPROJ: f32 D0 = auxf + acc
// EPI 2: GATE13: acc pairs (ni even=a, odd=c); store bf16 silu(a)*c to D0
// EPI 3: W2ACC: f32 D0 += acc
// ---------------------------------------------------------------------------
template<int EPI>
__global__ __launch_bounds__(256) void gemm_f(
    const unsigned short* __restrict__ A, const unsigned short* __restrict__ B,
    void* __restrict__ D0, void* __restrict__ D1, void* __restrict__ D2,
    const float* __restrict__ auxf, const float* __restrict__ cosT,
    const float* __restrict__ sinT, int M, int N, int K)
{
  __shared__ __align__(16) unsigned short As[128 * 64];
  __shared__ __align__(16) unsigned short Bs[128 * 64];
  const int tid = threadIdx.x, lane = tid & 63, w = tid >> 6;
  const int wr = w >> 1, wc = w & 1, l15 = lane & 15, lg = lane >> 4;
  const int m0 = blockIdx.x * 128, n0 = blockIdx.y * 128;

  // staging source: thread t covers LDS 16B slot (row = t>>3, slot = t&7) of
  // each 32-row round; source col-slot is slot ^ (row&7) (inverse swizzle).
  const int srow  = tid >> 3;
  const int scol8 = (tid & 7) ^ (srow & 7);
  const unsigned short* Asrc = A + (size_t)(m0 + srow) * K + scol8 * 8;
  const unsigned short* Bsrc = B + (size_t)(n0 + srow) * K + scol8 * 8;

  f32x4 zero = {0.f, 0.f, 0.f, 0.f};
  f32x4 acc[4][4];
#pragma unroll
  for (int i = 0; i < 4; i++)
#pragma unroll
    for (int j = 0; j < 4; j++) acc[i][j] = zero;

  for (int k0 = 0; k0 < K; k0 += 64) {
#pragma unroll
    for (int p = 0; p < 4; ++p) {
      gload16(Asrc + (size_t)(p * 32) * K + k0, As + (p * 256 + w * 64) * 8);
      gload16(Bsrc + (size_t)(p * 32) * K + k0, Bs + (p * 256 + w * 64) * 8);
    }
    __syncthreads();
    bf16x8 af[2][4], bfr[2][4];
#pragma unroll
    for (int kk = 0; kk < 2; ++kk) {
#pragma unroll
      for (int i = 0; i < 4; ++i) {
        int rA = wr * 64 + i * 16 + l15;
        af[kk][i]  = ldb8(As + rA * 64 + ((((kk << 2) | lg)) ^ (rA & 7)) * 8);
        int rB = wc * 64 + i * 16 + l15;
        bfr[kk][i] = ldb8(Bs + rB * 64 + ((((kk << 2) | lg)) ^ (rB & 7)) * 8);
      }
    }
#pragma unroll
    for (int kk = 0; kk < 2; ++kk)
#pragma unroll
      for (int mi = 0; mi < 4; mi++)
#pragma unroll
        for (int ni = 0; ni < 4; ni++)
          acc[mi][ni] = mfma16(af[kk][mi], bfr[kk][ni], acc[mi][ni]);
    __syncthreads();
  }

  // ---- epilogues. C/D layout: col = l15, row = lg*4 + r (per 16x16 frag)
  if constexpr (EPI == 0) {
    unsigned short* qd = (unsigned short*)D0;
    unsigned short* kd = (unsigned short*)D1;
    unsigned short* vd = (unsigned short*)D2;
#pragma unroll
    for (int mi = 0; mi < 4; mi++) {
#pragma unroll
      for (int ni = 0; ni < 4; ni++) {
        int col = n0 + wc * 64 + ni * 16 + l15;
#pragma unroll
        for (int r = 0; r < 4; r++) {
          int row = m0 + wr * 64 + mi * 16 + lg * 4 + r;
          float v = acc[mi][ni][r];
          if (col < 4096) {                       // wave-uniform branch
            int d = col & 127, pi = d >> 1, sp = row & 2047;
            float c = cosT[sp * 64 + pi], s = sinT[sp * 64 + pi];
            float part = __shfl_xor(v, 1);
            float res = (d & 1) ? (part * s + v * c) : (v * c - part * s);
            unsigned short* dst = (col < 2048) ? qd : kd;
            dst[(size_t)row * 2048 + (col & 2047)] = f2bfu(res);
          } else {
            int vdc = col - 4096;
            vd[((size_t)((row >> 11) * 2048 + vdc)) * 2048 + (row & 2047)] = f2bfu(v);
          }
        }
      }
    }
  } else if constexpr (EPI == 1 || EPI == 3) {
    float* O = (float*)D0;
#pragma unroll
    for (int mi = 0; mi < 4; mi++)
#pragma unroll
      for (int ni = 0; ni < 4; ni++) {
        int col = n0 + wc * 64 + ni * 16 + l15;
#pragma unroll
        for (int r = 0; r < 4; r++) {
          int row = m0 + wr * 64 + mi * 16 + lg * 4 + r;
          size_t ix = (size_t)row * 2048 + col;
          if constexpr (EPI == 1) O[ix] = auxf[ix] + acc[mi][ni][r];
          else                    O[ix] = O[ix] + acc[mi][ni][r];
        }
      }
  } else if constexpr (EPI == 2) {
    unsigned short* G = (unsigned short*)D0;
#pragma unroll
    for (int mi = 0; mi < 4; mi++)
#pragma unroll
      for (int nj = 0; nj < 2; nj++) {
        int outc = (4 * blockIdx.y + 2 * wc + nj) * 16 + l15;
#pragma unroll
        for (int r = 0; r < 4; r++) {
          int row = m0 + wr * 64 + mi * 16 + lg * 4 + r;
          float a = acc[mi][2 * nj][r];
          float c = acc[mi][2 * nj + 1][r];
          float sg = a / (1.0f + fexp(-a));
          G[(size_t)row * 5440 + outc] = f2bfu(sg * c);
        }
      }
  }
}

// ---------------------------------------------------------------------------
// RMSNorm: one block (256 thr) per row of 2048 f32 -> bf16 out
// ---------------------------------------------------------------------------
__global__ __launch_bounds__(256) void rmsnorm_k(
    const float* __restrict__ x, const float* __restrict__ g,
    unsigned short* __restrict__ out)
{
  int row = blockIdx.x, t = threadIdx.x;
  const float* xr = x + (size_t)row * 2048;
  f32x4 v0 = ((const f32x4*)xr)[t];
  f32x4 v1 = ((const f32x4*)xr)[t + 256];
  float ss = v0.x*v0.x + v0.y*v0.y + v0.z*v0.z + v0.w*v0.w
           + v1.x*v1.x + v1.y*v1.y + v1.z*v1.z + v1.w*v1.w;
  __shared__ float red[256];
  red[t] = ss; __syncthreads();
  for (int sh = 128; sh > 0; sh >>= 1) {
    if (t < sh) red[t] += red[t + sh];
    __syncthreads();
  }
  float rinv = rsqrtf(red[0] * (1.0f / 2048.0f) + 1e-5f);
  f32x4 g0 = ((const f32x4*)g)[t];
  f32x4 g1 = ((const f32x4*)g)[t + 256];
  u16x4 o0 = { f2bfu(v0.x*rinv*g0.x), f2bfu(v0.y*rinv*g0.y),
               f2bfu(v0.z*rinv*g0.z), f2bfu(v0.w*rinv*g0.w) };
  u16x4 o1 = { f2bfu(v1.x*rinv*g1.x), f2bfu(v1.y*rinv*g1.y),
               f2bfu(v1.z*rinv*g1.z), f2bfu(v1.w*rinv*g1.w) };
  *(u16x4*)(out + (size_t)row * 2048 + t * 4) = o0;
  *(u16x4*)(out + (size_t)row * 2048 + 1024 + t * 4) = o1;
}

__global__ __launch_bounds__(256) void rope_tab(float* __restrict__ cosT,
                                                float* __restrict__ sinT)
{
  int idx = blockIdx.x * 256 + threadIdx.x;
  int s = idx >> 6, p = idx & 63;
  float ang = (float)s * powf(10000.0f, -(float)p / 64.0f);
  cosT[idx] = cosf(ang);
  sinT[idx] = sinf(ang);
}

// ---------------------------------------------------------------------------
// Flash attention, causal. 4 waves/block, 64 q-rows per tile, KVBLK=64.
// Each block processes two q-tiles {bx, 31-bx} -> uniform work (33 kv-tiles).
// ---------------------------------------------------------------------------
__global__ __launch_bounds__(256) void attn_fwd(
    const unsigned short* __restrict__ q, const unsigned short* __restrict__ k,
    const unsigned short* __restrict__ vt, unsigned short* __restrict__ o)
{
  const int S = 2048, Dm = 2048;
  const int tid  = threadIdx.x;
  const int lane = tid & 63;
  const int w    = tid >> 6;
  const int hh   = blockIdx.y, b = blockIdx.z;
  const int l15  = lane & 15, lg = lane >> 4;
  const float SCALE = 0.08838834764831845f;  // 1/sqrt(128)

  __shared__ __align__(16) unsigned short Ks[64 * 128];
  __shared__ __align__(16) unsigned short Vs[128 * 64];
  __shared__ __align__(16) unsigned short Ps[4][16 * 76];

  const unsigned short* kg = k  + ((size_t)(b * S)) * Dm + hh * 128;
  const unsigned short* vg = vt + ((size_t)((b * 16 + hh) * 128)) * S;

  for (int half = 0; half < 2; ++half) {
    const int qt = half ? (31 - blockIdx.x) : blockIdx.x;
    const int r0 = qt * 64;

    bf16x8 qf[4];
    size_t qbase = ((size_t)(b * S + r0 + w * 16 + l15)) * Dm + hh * 128 + lg * 8;
#pragma unroll
    for (int kk = 0; kk < 4; kk++) qf[kk] = ldb8(q + qbase + kk * 32);

    f32x4 zero = {0.f, 0.f, 0.f, 0.f};
    f32x4 accO[8];
#pragma unroll
    for (int dt = 0; dt < 8; dt++) accO[dt] = zero;
    float mrow[4] = {-1e30f, -1e30f, -1e30f, -1e30f};
    float lrow[4] = {0.f, 0.f, 0.f, 0.f};

    int ntile = qt + 1;
    for (int j = 0; j < ntile; ++j) {
      int kv0 = j * 64;
#pragma unroll
      for (int i = 0; i < 4; i++) {
        int idx = i * 256 + tid;
        int row = idx >> 4, slot = idx & 15;
        u16x8 vv = *(const u16x8*)(kg + (size_t)(kv0 + row) * Dm + slot * 8);
        int boff = (row * 256 + slot * 16) ^ ((row & 7) << 4);
        *(u16x8*)((char*)Ks + boff) = vv;
      }
#pragma unroll
      for (int i = 0; i < 4; i++) {
        int idx = i * 256 + tid;
        int row = idx >> 3, slot = idx & 7;
        u16x8 vv = *(const u16x8*)(vg + (size_t)row * S + kv0 + slot * 8);
        int boff = (row * 128 + slot * 16) ^ ((row & 7) << 4);
        *(u16x8*)((char*)Vs + boff) = vv;
      }
      __syncthreads();

      f32x4 sfr[4];
#pragma unroll
      for (int sv = 0; sv < 4; sv++) sfr[sv] = zero;
#pragma unroll
      for (int kk = 0; kk < 4; kk++) {
#pragma unroll
        for (int sv = 0; sv < 4; sv++) {
          int row = sv * 16 + l15;
          int boff = (row * 256 + kk * 64 + lg * 16) ^ ((row & 7) << 4);
          bf16x8 kf = ldb8((const unsigned short*)((const char*)Ks + boff));
          sfr[sv] = mfma16(qf[kk], kf, sfr[sv]);
        }
      }

      float alpha[4];
      float pv[4][4];
#pragma unroll
      for (int r = 0; r < 4; r++) {
        int qr = r0 + w * 16 + lg * 4 + r;
        float a[4];
#pragma unroll
        for (int sv = 0; sv < 4; sv++)
          a[sv] = (kv0 + sv * 16 + l15 <= qr) ? sfr[sv][r] * SCALE : -1e30f;
        float mx = fmaxf(fmaxf(a[0], a[1]), fmaxf(a[2], a[3]));
#pragma unroll
        for (int off = 1; off < 16; off <<= 1) mx = fmaxf(mx, __shfl_xor(mx, off));
        float mnew = fmaxf(mrow[r], mx);
        alpha[r] = fexp(mrow[r] - mnew);
        float ps = 0.f;
#pragma unroll
        for (int sv = 0; sv < 4; sv++) { pv[r][sv] = fexp(a[sv] - mnew); ps += pv[r][sv]; }
#pragma unroll
        for (int off = 1; off < 16; off <<= 1) ps += __shfl_xor(ps, off);
        lrow[r] = lrow[r] * alpha[r] + ps;
        mrow[r] = mnew;
      }
#pragma unroll
      for (int dt = 0; dt < 8; dt++) {
        f32x4 t = accO[dt];
        t[0] *= alpha[0]; t[1] *= alpha[1]; t[2] *= alpha[2]; t[3] *= alpha[3];
        accO[dt] = t;
      }

#pragma unroll
      for (int r = 0; r < 4; r++)
#pragma unroll
        for (int sv = 0; sv < 4; sv++)
          Ps[w][(lg * 4 + r) * 76 + sv * 16 + l15] = f2bfu(pv[r][sv]);

      bf16x8 pa[2];
      pa[0] = ldb8(&Ps[w][l15 * 76 + lg * 8]);
      pa[1] = ldb8(&Ps[w][l15 * 76 + 32 + lg * 8]);
#pragma unroll
      for (int dt = 0; dt < 8; dt++) {
#pragma unroll
        for (int kk = 0; kk < 2; kk++) {
          int row = dt * 16 + l15;
          int boff = (row * 128 + kk * 64 + lg * 16) ^ ((row & 7) << 4);
          bf16x8 vb = ldb8((const unsigned short*)((const char*)Vs + boff));
          accO[dt] = mfma16(pa[kk], vb, accO[dt]);
        }
      }
      __syncthreads();
    }

#pragma unroll
    for (int dt = 0; dt < 8; dt++) {
#pragma unroll
      for (int r = 0; r < 4; r++) {
        int qr = r0 + w * 16 + lg * 4 + r;
        o[((size_t)(b * S + qr)) * Dm + hh * 128 + dt * 16 + l15] =
            f2bfu(accO[dt][r] / lrow[r]);
      }
    }
  }
}

// ---------------------------------------------------------------------------
extern "C" void kernel_launch(void* const* d_in, const int* in_sizes, int n_in,
                              void* d_out, int out_size, void* d_ws, size_t ws_size,
                              hipStream_t stream)
{
  const float* x      = (const float*)d_in[0];
  const float* wq     = (const float*)d_in[1];
  const float* wk     = (const float*)d_in[2];
  const float* wv     = (const float*)d_in[3];
  const float* wo     = (const float*)d_in[4];
  const float* w1     = (const float*)d_in[5];
  const float* w2     = (const float*)d_in[6];
  const float* w3     = (const float*)d_in[7];
  const float* g_attn = (const float*)d_in[8];
  const float* g_ffn  = (const float*)d_in[9];
  float* out = (float*)d_out;

  unsigned short* W = (unsigned short*)d_ws;
  unsigned short* h_bf    = W;                      // 8388608
  unsigned short* q_bf    = W + 8388608ull;
  unsigned short* k_bf    = W + 16777216ull;
  unsigned short* vt_bf   = W + 25165824ull;
  unsigned short* o_bf    = W + 33554432ull;
  unsigned short* wqkv_bf = W + 41943040ull;        // 12582912
  unsigned short* wo_bf   = W + 54525952ull;        // 4194304
  unsigned short* w13_bf  = W + 58720256ull;        // 22282240
  unsigned short* w2_bf   = W + 81002496ull;        // 11141120
  unsigned short* a1_bf   = q_bf;                   // alias: q/k/vt dead by then
  float* cosT = (float*)(W + 92143616ull);
  float* sinT = cosT + 131072;

  dim3 blk(256);
  rope_tab<<<512, blk, 0, stream>>>(cosT, sinT);
  conv_cat3<<<12288, blk, 0, stream>>>(wq, wk, wv, wqkv_bf);
  conv_plain<<<4096, blk, 0, stream>>>(wo, wo_bf);
  conv_w13<<<21760, blk, 0, stream>>>(w1, w3, w13_bf);
  conv_plain<<<10880, blk, 0, stream>>>(w2, w2_bf);

  rmsnorm_k<<<4096, blk, 0, stream>>>(x, g_attn, h_bf);

  gemm_f<0><<<dim3(32, 48), blk, 0, stream>>>(h_bf, wqkv_bf, q_bf, k_bf, vt_bf,
                                              nullptr, cosT, sinT, 4096, 6144, 2048);

  attn_fwd<<<dim3(16, 16, 2), blk, 0, stream>>>(q_bf, k_bf, vt_bf, o_bf);

  gemm_f<1><<<dim3(32, 16), blk, 0, stream>>>(o_bf, wo_bf, out, nullptr, nullptr,
                                              x, nullptr, nullptr, 4096, 2048, 2048);
  rmsnorm_k<<<4096, blk, 0, stream>>>(out, g_ffn, h_bf);

  gemm_f<2><<<dim3(32, 85), blk, 0, stream>>>(h_bf, w13_bf, a1_bf, nullptr, nullptr,
                                              nullptr, nullptr, nullptr, 4096, 10880, 2048);
  gemm_f<3><<<dim3(32, 16), blk, 0, stream>>>(a1_bf, w2_bf, out, nullptr, nullptr,
                                              nullptr, nullptr, nullptr, 4096, 2048, 5440);
}